// Round 1
// baseline (811.515 us; speedup 1.0000x reference)
//
#include <hip/hip_runtime.h>
#include <cstdint>
#include <cstddef>

#define TPB 256

// fc: feat0[n][b][c] = latents[b] . fc_W[:, n*64+c] + fc_b
__global__ __launch_bounds__(TPB) void k_fc(
    const float* __restrict__ lat, const float* __restrict__ W,
    const float* __restrict__ bias, float* __restrict__ out)
{
    int tid = blockIdx.x * TPB + threadIdx.x;   // 256*8*64 = 131072
    int c = tid & 63;
    int b = (tid >> 6) & 7;
    int n = tid >> 9;
    int j = n * 64 + c;
    float acc = bias[j];
    const float* lb = lat + b * 64;
#pragma unroll 16
    for (int l = 0; l < 64; ++l)
        acc = fmaf(lb[l], W[l * 16384 + j], acc);
    out[tid] = acc;
}

// Y[nb][co] = X[nb][:] . W[:][co]   (used for feat@W and Ub@W)
template<int CI, int CO>
__global__ __launch_bounds__(TPB) void k_matw(
    const float* __restrict__ X, const float* __restrict__ W,
    float* __restrict__ Y, int NB)
{
    int tid = blockIdx.x * TPB + threadIdx.x;
    if (tid >= NB * CO) return;
    int co = tid % CO;
    int nb = tid / CO;
    const float* x = X + (size_t)nb * CI;
    float acc = 0.f;
#pragma unroll
    for (int ci = 0; ci < CI; ++ci)
        acc = fmaf(x[ci], W[ci * CO + co], acc);
    Y[tid] = acc;
}

__global__ __launch_bounds__(TPB) void k_zero2(float* a, int na, float* b, int nb)
{
    int tid = blockIdx.x * TPB + threadIdx.x;
    if (tid < na) a[tid] = 0.f;
    if (tid < nb) b[tid] = 0.f;
}

// up[row][s*CS + j] = sum_k U[row][k] * fW[k][s*CS + j]  (+ UbW[row][j%CO] once)
// One thread per row; K split over blockIdx.z, partials via atomicAdd.
template<int K, int BC, int CO, int CS, int KSPLIT>
__global__ __launch_bounds__(TPB) void k_upgemm(
    const float* __restrict__ U, const float* __restrict__ fW,
    const float* __restrict__ UbW, float* __restrict__ up)
{
    static_assert(CS % CO == 0, "UbW fold assumes CS multiple of CO");
    constexpr int KC = K / KSPLIT;
    const int row = blockIdx.x * TPB + threadIdx.x;
    const int s = blockIdx.y;
    const int kz = blockIdx.z;
    const float* __restrict__ Urow = U + (size_t)row * K + (size_t)kz * KC;
    const float* __restrict__ fbase = fW + (size_t)kz * KC * BC + (size_t)s * CS;
    float acc[CS];
#pragma unroll
    for (int j = 0; j < CS; ++j) acc[j] = 0.f;
    for (int k = 0; k < KC; k += 16) {
        float4 u0 = *reinterpret_cast<const float4*>(Urow + k);
        float4 u1 = *reinterpret_cast<const float4*>(Urow + k + 4);
        float4 u2 = *reinterpret_cast<const float4*>(Urow + k + 8);
        float4 u3 = *reinterpret_cast<const float4*>(Urow + k + 12);
        const float* __restrict__ f0 = fbase + (size_t)k * BC;
        float uu[16] = {u0.x,u0.y,u0.z,u0.w, u1.x,u1.y,u1.z,u1.w,
                        u2.x,u2.y,u2.z,u2.w, u3.x,u3.y,u3.z,u3.w};
#pragma unroll
        for (int t = 0; t < 16; ++t) {
#pragma unroll
            for (int j = 0; j < CS; ++j)
                acc[j] = fmaf(uu[t], f0[(size_t)t * BC + j], acc[j]);
        }
    }
    if (kz == 0) {
#pragma unroll
        for (int j = 0; j < CS; ++j)
            acc[j] += UbW[(size_t)row * CO + (j % CO)];
    }
    float* o = up + (size_t)row * BC + (size_t)s * CS;
#pragma unroll
    for (int j = 0; j < CS; ++j) atomicAdd(o + j, acc[j]);
}

// agg[rows[e]][j] += vals[e] * up[cols[e]][j], one thread per (e, j)
template<int BC>
__global__ __launch_bounds__(TPB) void k_scatter(
    const float* __restrict__ up, const int* __restrict__ rows,
    const int* __restrict__ cols, const float* __restrict__ vals,
    float* __restrict__ agg, int E)
{
    int tid = blockIdx.x * TPB + threadIdx.x;
    if (tid >= E * BC) return;
    int e = tid / BC;
    int j = tid % BC;
    float v = vals[e];
    int c = cols[e], r = rows[e];
    atomicAdd(&agg[(size_t)r * BC + j], v * up[(size_t)c * BC + j]);
}

template<int CO>
__global__ __launch_bounds__(TPB) void k_relu_bias(
    const float* __restrict__ agg, const float* __restrict__ bias,
    float* __restrict__ out, int n)
{
    int tid = blockIdx.x * TPB + threadIdx.x;
    if (tid >= n) return;
    float x = agg[tid] + bias[tid % CO];
    out[tid] = fmaxf(x, 0.f);
}

// out[b][n][j] = relu(agg[n][b*3+j] + bias[j]),  agg: [16384][24]
__global__ __launch_bounds__(TPB) void k_out(
    const float* __restrict__ agg, const float* __restrict__ bias,
    float* __restrict__ out)
{
    int tid = blockIdx.x * TPB + threadIdx.x;   // 393216
    int j = tid % 3;
    int n = (tid / 3) & 16383;
    int b = tid / 49152;
    float x = agg[(size_t)n * 24 + b * 3 + j] + bias[j];
    out[tid] = fmaxf(x, 0.f);
}

extern "C" void kernel_launch(void* const* d_in, const int* in_sizes, int n_in,
                              void* d_out, int out_size, void* d_ws, size_t ws_size,
                              hipStream_t stream)
{
    const float* lat   = (const float*)d_in[0];
    const float* fcW   = (const float*)d_in[1];
    const float* fcb   = (const float*)d_in[2];
    const float* U0    = (const float*)d_in[3];
    const float* Ub0   = (const float*)d_in[4];
    const float* W0    = (const float*)d_in[5];
    const float* b0    = (const float*)d_in[6];
    const float* vals0 = (const float*)d_in[7];
    const int*   rows0 = (const int*)d_in[8];
    const int*   cols0 = (const int*)d_in[9];
    const float* U1    = (const float*)d_in[10];
    const float* Ub1   = (const float*)d_in[11];
    const float* W1    = (const float*)d_in[12];
    const float* b1    = (const float*)d_in[13];
    const float* vals1 = (const float*)d_in[14];
    const int*   rows1 = (const int*)d_in[15];
    const int*   cols1 = (const int*)d_in[16];
    const float* U2    = (const float*)d_in[17];
    const float* Ub2   = (const float*)d_in[18];
    const float* W2    = (const float*)d_in[19];
    const float* b2    = (const float*)d_in[20];
    const float* vals2 = (const float*)d_in[21];
    const int*   rows2 = (const int*)d_in[22];
    const int*   cols2 = (const int*)d_in[23];

    float* ws    = (float*)d_ws;
    float* featA = ws;                  // 1048576 floats
    float* featB = featA + 1048576;     // 1048576
    float* fWb   = featB + 1048576;     // 262144
    float* UbWb  = fWb   + 262144;      // 131072
    float* up    = UbWb  + 131072;      // 1048576
    float* agg   = up    + 1048576;     // 1048576

    float* out = (float*)d_out;

    // fc -> featA = feat0 [256][8][64]
    hipLaunchKernelGGL(k_fc, dim3(131072 / TPB), dim3(TPB), 0, stream, lat, fcW, fcb, featA);

    // ---- layer 0: CI=64 CO=64 K=256 M=1024 BC=512 ----
    hipLaunchKernelGGL((k_matw<64, 64>), dim3(131072 / TPB), dim3(TPB), 0, stream, featA, W0, fWb, 2048);
    hipLaunchKernelGGL((k_matw<64, 64>), dim3(65536 / TPB), dim3(TPB), 0, stream, Ub0, W0, UbWb, 1024);
    hipLaunchKernelGGL(k_zero2, dim3(524288 / TPB), dim3(TPB), 0, stream, up, 524288, agg, 524288);
    hipLaunchKernelGGL((k_upgemm<256, 512, 64, 64, 4>), dim3(4, 8, 4), dim3(TPB), 0, stream, U0, fWb, UbWb, up);
    hipLaunchKernelGGL((k_scatter<512>), dim3(8388608 / TPB), dim3(TPB), 0, stream, up, rows0, cols0, vals0, agg, 16384);
    hipLaunchKernelGGL((k_relu_bias<64>), dim3(524288 / TPB), dim3(TPB), 0, stream, agg, b0, featB, 524288);

    // ---- layer 1: CI=64 CO=32 K=1024 M=4096 BC=256 ----
    hipLaunchKernelGGL((k_matw<64, 32>), dim3(262144 / TPB), dim3(TPB), 0, stream, featB, W1, fWb, 8192);
    hipLaunchKernelGGL((k_matw<64, 32>), dim3(131072 / TPB), dim3(TPB), 0, stream, Ub1, W1, UbWb, 4096);
    hipLaunchKernelGGL(k_zero2, dim3(1048576 / TPB), dim3(TPB), 0, stream, up, 1048576, agg, 1048576);
    hipLaunchKernelGGL((k_upgemm<1024, 256, 32, 64, 4>), dim3(16, 4, 4), dim3(TPB), 0, stream, U1, fWb, UbWb, up);
    hipLaunchKernelGGL((k_scatter<256>), dim3(16777216 / TPB), dim3(TPB), 0, stream, up, rows1, cols1, vals1, agg, 65536);
    hipLaunchKernelGGL((k_relu_bias<32>), dim3(1048576 / TPB), dim3(TPB), 0, stream, agg, b1, featA, 1048576);

    // ---- layer 2: CI=32 CO=3 K=4096 M=16384 BC=24 ----
    hipLaunchKernelGGL((k_matw<32, 3>), dim3((98304 + TPB - 1) / TPB), dim3(TPB), 0, stream, featA, W2, fWb, 32768);
    hipLaunchKernelGGL((k_matw<32, 3>), dim3((49152 + TPB - 1) / TPB), dim3(TPB), 0, stream, Ub2, W2, UbWb, 16384);
    hipLaunchKernelGGL(k_zero2, dim3(393216 / TPB), dim3(TPB), 0, stream, up, 393216, agg, 393216);
    hipLaunchKernelGGL((k_upgemm<4096, 24, 3, 24, 8>), dim3(64, 1, 8), dim3(TPB), 0, stream, U2, fWb, UbWb, up);
    hipLaunchKernelGGL((k_scatter<24>), dim3(6291456 / TPB), dim3(TPB), 0, stream, up, rows2, cols2, vals2, agg, 262144);
    hipLaunchKernelGGL(k_out, dim3(393216 / TPB), dim3(TPB), 0, stream, agg, b2, out);
}